// Round 2
// baseline (2315.676 us; speedup 1.0000x reference)
//
#include <hip/hip_runtime.h>
#include <cstdint>

#define B_  8
#define V_  50000
#define C_  256
#define K_  9
#define PC  64
#define R1  16   // rows per block, kernel1
#define R2  16   // rows per block, kernel2
#define CT  32   // c-tile width, kernel2

// ---------------------------------------------------------------------------
// Kernel 1: p[row][o] = sum_{k,c} x[b, idx[v,k], c] * W1[o, k*64+c] + b1[o]
// p is written into out[row*256 + o] for o in [0,64) (out used as scratch).
// NOTE: harness delivers integer inputs as int32 (reference int64 is
// converted) — cast d_in[1] to const int*.
// ---------------------------------------------------------------------------
__global__ __launch_bounds__(256) void k1_gather_gemm(
    const float* __restrict__ x, const int* __restrict__ idx,
    const float* __restrict__ W1, const float* __restrict__ b1,
    float* __restrict__ out)
{
    __shared__ float g[R1][PC];         // gathered chunk for current k (4 KB)
    __shared__ float w1t[PC][PC + 1];   // transposed W1 tile: w1t[c][o] (16.6 KB)
    __shared__ int   idxs[R1][K_];

    const int tid = threadIdx.x;
    const int rowBase = blockIdx.x * R1;

    // stage the 16 rows' 9 indices
    if (tid < R1 * K_) {
        int r = tid / K_, k = tid % K_;
        int row = rowBase + r;
        int v = row % V_;
        idxs[r][k] = idx[v * K_ + k];
    }
    __syncthreads();

    const int o  = tid & 63;   // output channel / c-lane
    const int rq = tid >> 6;   // wave id 0..3
    float acc[4] = {0.f, 0.f, 0.f, 0.f};

    for (int k = 0; k < K_; ++k) {
        // gather: wave rq loads rows rq, rq+4, rq+8, rq+12 (64 floats each, coalesced)
        #pragma unroll
        for (int j = 0; j < 4; ++j) {
            int r = rq + j * 4;
            int row = rowBase + r;
            int b = row / V_;
            int src = (b * V_ + idxs[r][k]) * C_ + o;
            g[r][o] = x[src];
        }
        // stage W1 tile transposed: w1t[c][o] = W1[o][k*64+c]
        #pragma unroll
        for (int j = 0; j < 16; ++j) {
            int e  = j * 256 + tid;      // 0..4095
            int oo = e >> 6, cc = e & 63;
            w1t[cc][oo] = W1[oo * (K_ * PC) + k * PC + cc];
        }
        __syncthreads();

        // compute: rows rq*4 .. rq*4+3 (wave-uniform broadcast), output o
        #pragma unroll 8
        for (int c = 0; c < PC; ++c) {
            float w = w1t[c][o];         // lane-consecutive -> conflict-free
            #pragma unroll
            for (int j = 0; j < 4; ++j)
                acc[j] += g[rq * 4 + j][c] * w;   // broadcast
        }
        __syncthreads();
    }

    float bb = b1[o];
    #pragma unroll
    for (int j = 0; j < 4; ++j) {
        int row = rowBase + rq * 4 + j;
        out[row * C_ + o] = acc[j] + bb;   // coalesced
    }
}

// ---------------------------------------------------------------------------
// Kernel 2: out[row][o] = sum_c xcat[row][c] * W2[o][c] + b2[o]
// xcat[c<64] = p (read from out scratch), xcat[c>=64] = x[row][c].
// ---------------------------------------------------------------------------
__global__ __launch_bounds__(256) void k2_gemm(
    const float* __restrict__ x, const float* __restrict__ W2,
    const float* __restrict__ b2, float* __restrict__ out)
{
    __shared__ float xc[R2][C_];          // 16 KB
    __shared__ float w2t[CT][C_ + 1];     // transposed W2 c-tile (32.9 KB)

    const int tid = threadIdx.x;
    const int rowBase = blockIdx.x * R2;

    // load x_cat tile: c<64 from out (p), c>=64 from x — branch is wave-uniform
    #pragma unroll
    for (int j = 0; j < 16; ++j) {
        int e = j * 256 + tid;            // 0..4095
        int r = e >> 8, c = e & 255;
        int row = rowBase + r;
        float v;
        if (c < PC) v = out[row * C_ + c];
        else        v = x[row * C_ + c];
        xc[r][c] = v;
    }

    const int ol = tid & 63;
    const int rq = tid >> 6;
    float acc[4][4];
    #pragma unroll
    for (int i = 0; i < 4; ++i)
        #pragma unroll
        for (int j = 0; j < 4; ++j) acc[i][j] = 0.f;

    for (int ct = 0; ct < C_ / CT; ++ct) {   // 8 tiles of 32
        __syncthreads();  // protect w2t from previous iteration's readers (and xc on first iter)
        // stage w2t[c][o] = W2[o][ct*32 + c]
        #pragma unroll
        for (int j = 0; j < 32; ++j) {
            int e  = j * 256 + tid;       // 0..8191
            int oo = e >> 5, cc = e & 31;
            w2t[cc][oo] = W2[oo * C_ + ct * CT + cc];
        }
        __syncthreads();

        #pragma unroll 8
        for (int c = 0; c < CT; ++c) {
            float w[4], gj[4];
            #pragma unroll
            for (int i = 0; i < 4; ++i) w[i] = w2t[c][ol + 64 * i];   // conflict-free
            #pragma unroll
            for (int j = 0; j < 4; ++j) gj[j] = xc[rq * 4 + j][ct * CT + c]; // broadcast
            #pragma unroll
            for (int i = 0; i < 4; ++i)
                #pragma unroll
                for (int j = 0; j < 4; ++j)
                    acc[i][j] += gj[j] * w[i];
        }
    }

    #pragma unroll
    for (int j = 0; j < 4; ++j) {
        int row = rowBase + rq * 4 + j;
        #pragma unroll
        for (int i = 0; i < 4; ++i) {
            int o = ol + 64 * i;
            out[row * C_ + o] = acc[i][j] + b2[o];   // coalesced
        }
    }
}

// ---------------------------------------------------------------------------
extern "C" void kernel_launch(void* const* d_in, const int* in_sizes, int n_in,
                              void* d_out, int out_size, void* d_ws, size_t ws_size,
                              hipStream_t stream) {
    const float* x   = (const float*)d_in[0];
    const int*   idx = (const int*)d_in[1];      // int64 in reference -> int32 on device
    const float* W1  = (const float*)d_in[2];
    const float* b1  = (const float*)d_in[3];
    const float* W2  = (const float*)d_in[4];
    const float* b2  = (const float*)d_in[5];
    float* out = (float*)d_out;

    const int rows = B_ * V_;            // 400000
    k1_gather_gemm<<<rows / R1, 256, 0, stream>>>(x, idx, W1, b1, out);
    k2_gemm<<<rows / R2, 256, 0, stream>>>(x, W2, b2, out);
}